// Round 4
// baseline (103.601 us; speedup 1.0000x reference)
//
#include <hip/hip_runtime.h>

typedef __attribute__((ext_vector_type(8))) short short8;
typedef __attribute__((ext_vector_type(4))) float f32x4;
typedef __attribute__((ext_vector_type(4))) int i32x4;

// fp32 -> bf16 round-to-nearest-even
__device__ __forceinline__ unsigned short f2bf(float f) {
  unsigned u = __builtin_bit_cast(unsigned, f);
  u += 0x7fffu + ((u >> 16) & 1u);
  return (unsigned short)(u >> 16);
}

// ---------------------------------------------------------------------------
// prep: blocks [0,512): per-(b,i) stats + exact fp32 copies.
// blocks [512,1664): W1..W4 fp32 -> bf16, MFMA B-fragment swizzle.
// ---------------------------------------------------------------------------
__global__ __launch_bounds__(256) void prep(
    const float* __restrict__ user, const float* __restrict__ ris,
    const float* __restrict__ W1, const float* __restrict__ W2,
    const float* __restrict__ W3, const float* __restrict__ W4,
    unsigned short* __restrict__ m1b, unsigned short* __restrict__ m2b,
    int* __restrict__ am, unsigned short* __restrict__ meanb,
    unsigned short* __restrict__ risb,
    unsigned short* __restrict__ W1f, unsigned short* __restrict__ W2f,
    unsigned short* __restrict__ W3f, unsigned short* __restrict__ W4f,
    float* __restrict__ out0, float* __restrict__ out1) {
  if (blockIdx.x < 512) {
    int idx = blockIdx.x * 256 + threadIdx.x;  // 0..131071 (B*IN)
    int b = idx >> 7, i = idx & 127;
    const float* up = user + (size_t)(b * 64) * 128 + i;
    float* op = out0 + (size_t)(b * 64) * 384 + i;
    float s = 0.f, m1 = -3.402823466e38f, m2 = -3.402823466e38f;
    int amx = 0;
    #pragma unroll 8
    for (int k = 0; k < 64; ++k) {
      float u = up[(size_t)k * 128];
      op[(size_t)k * 384] = u;   // exact fp32 copy
      s += u;
      if (u > m1) { m2 = m1; m1 = u; amx = k; }
      else if (u > m2) { m2 = u; }
    }
    m1b[idx] = f2bf(m1);
    m2b[idx] = f2bf(m2);
    am[idx] = amx;
    meanb[idx] = f2bf(s * (1.f / 64.f));
    float rv = ris[idx];
    out1[(size_t)b * 384 + i] = rv;  // exact fp32 copy
    risb[idx] = f2bf(rv);
  } else {
    int idx = (blockIdx.x - 512) * 256 + threadIdx.x;  // 0..294911
    const float* src; unsigned short* dst; int kb; int rel;
    if (idx < 98304)        { src = W1; dst = W1f; kb = 12; rel = idx; }
    else if (idx < 163840)  { src = W2; dst = W2f; kb = 8;  rel = idx - 98304; }
    else if (idx < 229376)  { src = W3; dst = W3f; kb = 8;  rel = idx - 163840; }
    else                    { src = W4; dst = W4f; kb = 8;  rel = idx - 229376; }
    int kk = rel >> 8, n = rel & 255;
    int lane = (n & 15) | (((kk >> 3) & 3) << 4);
    int di = (((n >> 4) * kb + (kk >> 5)) * 64 + lane) * 8 + (kk & 7);
    dst[di] = f2bf(src[rel]);
  }
}

// ===========================================================================
// Path A (needs ~34.6 MB ws): two GEMM kernels with weights in LDS.
// ===========================================================================

// L1: C1 = relu(A @ Wa + ba) -> H (bf16, col-quarter-tiled layout
// H[q][row][64]). Block = 256 rows x 64 cols (one quarter), 4 waves M-split.
// Weight quarter staged once in LDS; one barrier; then waves free-run.
template<int MODE>
__device__ __forceinline__ void l1_body(
    int q, int rg, unsigned short* __restrict__ Wl,
    const float* __restrict__ user,
    const unsigned short* __restrict__ m1b, const unsigned short* __restrict__ m2b,
    const int* __restrict__ am,
    const unsigned short* __restrict__ risb, const unsigned short* __restrict__ meanb,
    const unsigned short* __restrict__ Wsrc, const float* __restrict__ bsrc,
    unsigned short* __restrict__ Hdst) {
  constexpr int NFS = (MODE == 0) ? 12 : 8;   // K/32
  constexpr int NR  = (MODE == 0) ? 65536 : 1024;
  const int tid = threadIdx.x;

  // stage weight quarter slab: NFS*8KB/2... = NFS iters x 256 thr x 16B
  #pragma unroll
  for (int it = 0; it < NFS; ++it)
    ((i32x4*)Wl)[it * 256 + tid] = ((const i32x4*)Wsrc)[it * 256 + tid];
  __syncthreads();

  const int lane = tid & 63, w = tid >> 6;
  const int r = lane & 15;
  const int k8 = (lane >> 4) * 8;
  const int row0 = rg * 256 + w * 64;
  const int b = row0 >> 6;                    // batch (MODE 0): one per wave

  f32x4 acc[4][4];
  #pragma unroll
  for (int a = 0; a < 4; ++a)
    #pragma unroll
    for (int p = 0; p < 4; ++p) acc[a][p] = (f32x4)0.f;

  #pragma unroll
  for (int fs = 0; fs < NFS; ++fs) {
    short8 af[4];
    if constexpr (MODE == 0) {
      if (fs < 4) {               // user chunk (fp32 -> bf16 in-reg)
        #pragma unroll
        for (int mf = 0; mf < 4; ++mf) {
          const float* p = &user[(size_t)(row0 + mf * 16 + r) * 128 + fs * 32 + k8];
          f32x4 t0 = *(const f32x4*)p;
          f32x4 t1 = *(const f32x4*)(p + 4);
          short8 t;
          #pragma unroll
          for (int j = 0; j < 4; ++j) { t[j] = (short)f2bf(t0[j]); t[4 + j] = (short)f2bf(t1[j]); }
          af[mf] = t;
        }
      } else if (fs < 8) {        // leave-one-out max from stats
        int c0 = b * 128 + (fs - 4) * 32 + k8;
        short8 m1v = *(const short8*)&m1b[c0];
        short8 m2v = *(const short8*)&m2b[c0];
        i32x4 a0 = *(const i32x4*)&am[c0];
        i32x4 a1 = *(const i32x4*)&am[c0 + 4];
        #pragma unroll
        for (int mf = 0; mf < 4; ++mf) {
          int rr = mf * 16 + r;
          short8 t;
          #pragma unroll
          for (int j = 0; j < 4; ++j) {
            t[j]     = (a0[j] == rr) ? m2v[j]     : m1v[j];
            t[4 + j] = (a1[j] == rr) ? m2v[4 + j] : m1v[4 + j];
          }
          af[mf] = t;
        }
      } else {                    // RIS broadcast chunk
        short8 v = *(const short8*)&risb[b * 128 + (fs - 8) * 32 + k8];
        #pragma unroll
        for (int mf = 0; mf < 4; ++mf) af[mf] = v;
      }
    } else {
      const unsigned short* src = (fs < 4) ? risb : meanb;
      #pragma unroll
      for (int mf = 0; mf < 4; ++mf)
        af[mf] = *(const short8*)&src[(size_t)(row0 + mf * 16 + r) * 128 + (fs & 3) * 32 + k8];
    }
    short8 bfr[4];
    #pragma unroll
    for (int nf = 0; nf < 4; ++nf)
      bfr[nf] = *(const short8*)&Wl[((nf * NFS + fs) * 64 + lane) * 8];
    #pragma unroll
    for (int mf = 0; mf < 4; ++mf)
      #pragma unroll
      for (int nf = 0; nf < 4; ++nf)
        acc[mf][nf] = __builtin_amdgcn_mfma_f32_16x16x32_bf16(af[mf], bfr[nf], acc[mf][nf], 0, 0, 0);
  }

  // epilogue: bias + relu -> H quarter tile (bf16)
  float bav[4];
  #pragma unroll
  for (int nf = 0; nf < 4; ++nf) bav[nf] = bsrc[q * 64 + nf * 16 + (lane & 15)];
  #pragma unroll
  for (int mf = 0; mf < 4; ++mf)
    #pragma unroll
    for (int nf = 0; nf < 4; ++nf)
      #pragma unroll
      for (int j = 0; j < 4; ++j) {
        int row = row0 + mf * 16 + ((lane >> 4) * 4) + j;
        int c = nf * 16 + (lane & 15);
        Hdst[((size_t)q * NR + row) * 64 + c] = f2bf(fmaxf(acc[mf][nf][j] + bav[nf], 0.f));
      }
}

__global__ __launch_bounds__(256, 3) void l1k(
    const float* __restrict__ user,
    const unsigned short* __restrict__ m1b, const unsigned short* __restrict__ m2b,
    const int* __restrict__ am,
    const unsigned short* __restrict__ risb, const unsigned short* __restrict__ meanb,
    const unsigned short* __restrict__ W1f, const unsigned short* __restrict__ W3f,
    const float* __restrict__ b1, const float* __restrict__ b3,
    unsigned short* __restrict__ Hu, unsigned short* __restrict__ Hr) {
  __shared__ unsigned short Wl[12 * 2048];   // 48 KiB max
  int bid = blockIdx.x;
  if (bid < 1024) {
    int q = bid & 3, rg = bid >> 2;
    l1_body<0>(q, rg, Wl, user, m1b, m2b, am, risb, meanb,
               W1f + (size_t)q * 4 * 12 * 512, b1, Hu);
  } else {
    int b2 = bid - 1024;
    int q = b2 & 3, rg = b2 >> 2;
    l1_body<1>(q, rg, Wl, user, m1b, m2b, am, risb, meanb,
               W3f + (size_t)q * 4 * 8 * 512, b3, Hr);
  }
}

// L2: out_cols[128..383] = H @ Wb + bb. Block = 256 rows x 64 cols (quarter),
// 4 waves M-split; Wb quarter (32 KiB) in LDS.
template<int MODE>
__device__ __forceinline__ void l2_body(
    int q, int rg, unsigned short* __restrict__ Wl,
    const unsigned short* __restrict__ H,
    const unsigned short* __restrict__ Wsrc, const float* __restrict__ bsrc,
    float* __restrict__ out) {
  constexpr int NR = (MODE == 0) ? 65536 : 1024;
  const int tid = threadIdx.x;

  #pragma unroll
  for (int it = 0; it < 8; ++it)
    ((i32x4*)Wl)[it * 256 + tid] = ((const i32x4*)Wsrc)[it * 256 + tid];
  __syncthreads();

  const int lane = tid & 63, w = tid >> 6;
  const int r = lane & 15;
  const int k8 = (lane >> 4) * 8;
  const int row0 = rg * 256 + w * 64;

  f32x4 acc[4][4];
  #pragma unroll
  for (int a = 0; a < 4; ++a)
    #pragma unroll
    for (int p = 0; p < 4; ++p) acc[a][p] = (f32x4)0.f;

  #pragma unroll
  for (int kc = 0; kc < 8; ++kc) {
    short8 af[4], bfr[4];
    #pragma unroll
    for (int mf = 0; mf < 4; ++mf)
      af[mf] = *(const short8*)&H[((size_t)(kc >> 1) * NR + row0 + mf * 16 + r) * 64 +
                                  (kc & 1) * 32 + k8];
    #pragma unroll
    for (int nf = 0; nf < 4; ++nf)
      bfr[nf] = *(const short8*)&Wl[((nf * 8 + kc) * 64 + lane) * 8];
    #pragma unroll
    for (int mf = 0; mf < 4; ++mf)
      #pragma unroll
      for (int nf = 0; nf < 4; ++nf)
        acc[mf][nf] = __builtin_amdgcn_mfma_f32_16x16x32_bf16(af[mf], bfr[nf], acc[mf][nf], 0, 0, 0);
  }

  float bbv[4];
  #pragma unroll
  for (int nf = 0; nf < 4; ++nf) bbv[nf] = bsrc[q * 64 + nf * 16 + (lane & 15)];
  #pragma unroll
  for (int mf = 0; mf < 4; ++mf)
    #pragma unroll
    for (int nf = 0; nf < 4; ++nf)
      #pragma unroll
      for (int j = 0; j < 4; ++j) {
        int row = row0 + mf * 16 + ((lane >> 4) * 4) + j;
        int c = nf * 16 + (lane & 15);
        out[(size_t)row * 384 + 128 + q * 64 + c] = acc[mf][nf][j] + bbv[nf];
      }
}

__global__ __launch_bounds__(256, 4) void l2k(
    const unsigned short* __restrict__ Hu, const unsigned short* __restrict__ Hr,
    const unsigned short* __restrict__ W2f, const unsigned short* __restrict__ W4f,
    const float* __restrict__ b2, const float* __restrict__ b4,
    float* __restrict__ out0, float* __restrict__ out1) {
  __shared__ unsigned short Wl[8 * 2048];    // 32 KiB
  int bid = blockIdx.x;
  if (bid < 1024) {
    int q = bid & 3, rg = bid >> 2;
    l2_body<0>(q, rg, Wl, Hu, W2f + (size_t)q * 4 * 8 * 512, b2, out0);
  } else {
    int b2_ = bid - 1024;
    int q = b2_ & 3, rg = b2_ >> 2;
    l2_body<1>(q, rg, Wl, Hr, W4f + (size_t)q * 4 * 8 * 512, b4, out1);
  }
}

// ===========================================================================
// Path B fallback (small ws): round-3 fused kernel (A direct-from-global,
// H in LDS, single barrier).
// ===========================================================================
template<int MODE>
__device__ __forceinline__ void mlp_body(
    int bx, unsigned short* __restrict__ Hb,
    const float* __restrict__ user,
    const unsigned short* __restrict__ m1b, const unsigned short* __restrict__ m2b,
    const int* __restrict__ am,
    const unsigned short* __restrict__ risb, const unsigned short* __restrict__ meanb,
    const unsigned short* __restrict__ Wa, const unsigned short* __restrict__ Wb,
    const float* __restrict__ ba, const float* __restrict__ bb,
    float* __restrict__ out) {
  constexpr int NFS = (MODE == 0) ? 12 : 8;
  const int tid = threadIdx.x;
  const int lane = tid & 63, wn = tid >> 6;
  const int row0 = bx * 64;
  const int r = lane & 15;
  const int k8 = (lane >> 4) * 8;

  f32x4 acc[4][4];
  #pragma unroll
  for (int a = 0; a < 4; ++a)
    #pragma unroll
    for (int p = 0; p < 4; ++p) acc[a][p] = (f32x4)0.f;

  #pragma unroll
  for (int fs = 0; fs < NFS; ++fs) {
    short8 af[4];
    if constexpr (MODE == 0) {
      if (fs < 4) {
        #pragma unroll
        for (int mf = 0; mf < 4; ++mf) {
          const float* p = &user[(size_t)(row0 + mf * 16 + r) * 128 + fs * 32 + k8];
          f32x4 t0 = *(const f32x4*)p;
          f32x4 t1 = *(const f32x4*)(p + 4);
          short8 t;
          #pragma unroll
          for (int j = 0; j < 4; ++j) { t[j] = (short)f2bf(t0[j]); t[4 + j] = (short)f2bf(t1[j]); }
          af[mf] = t;
        }
      } else if (fs < 8) {
        int c0 = bx * 128 + (fs - 4) * 32 + k8;
        short8 m1v = *(const short8*)&m1b[c0];
        short8 m2v = *(const short8*)&m2b[c0];
        i32x4 a0 = *(const i32x4*)&am[c0];
        i32x4 a1 = *(const i32x4*)&am[c0 + 4];
        #pragma unroll
        for (int mf = 0; mf < 4; ++mf) {
          int rr = mf * 16 + r;
          short8 t;
          #pragma unroll
          for (int j = 0; j < 4; ++j) {
            t[j]     = (a0[j] == rr) ? m2v[j]     : m1v[j];
            t[4 + j] = (a1[j] == rr) ? m2v[4 + j] : m1v[4 + j];
          }
          af[mf] = t;
        }
      } else {
        short8 v = *(const short8*)&risb[bx * 128 + (fs - 8) * 32 + k8];
        #pragma unroll
        for (int mf = 0; mf < 4; ++mf) af[mf] = v;
      }
    } else {
      const unsigned short* src = (fs < 4) ? risb : meanb;
      #pragma unroll
      for (int mf = 0; mf < 4; ++mf)
        af[mf] = *(const short8*)&src[(size_t)(row0 + mf * 16 + r) * 128 + (fs & 3) * 32 + k8];
    }
    short8 bfr[4];
    #pragma unroll
    for (int nf = 0; nf < 4; ++nf)
      bfr[nf] = *(const short8*)&Wa[(size_t)(((wn * 4 + nf) * NFS + fs) * 64 + lane) * 8];
    #pragma unroll
    for (int mf = 0; mf < 4; ++mf)
      #pragma unroll
      for (int nf = 0; nf < 4; ++nf)
        acc[mf][nf] = __builtin_amdgcn_mfma_f32_16x16x32_bf16(af[mf], bfr[nf], acc[mf][nf], 0, 0, 0);
  }

  float bav[4];
  #pragma unroll
  for (int nf = 0; nf < 4; ++nf) bav[nf] = ba[wn * 64 + nf * 16 + (lane & 15)];
  #pragma unroll
  for (int mf = 0; mf < 4; ++mf)
    #pragma unroll
    for (int nf = 0; nf < 4; ++nf)
      #pragma unroll
      for (int j = 0; j < 4; ++j) {
        int rr = mf * 16 + ((lane >> 4) * 4) + j;
        int col = wn * 64 + nf * 16 + (lane & 15);
        int c = col >> 3;
        Hb[rr * 256 + ((c ^ (rr & 7)) << 3) + (col & 7)] =
            f2bf(fmaxf(acc[mf][nf][j] + bav[nf], 0.f));
      }
  __syncthreads();

  #pragma unroll
  for (int a = 0; a < 4; ++a)
    #pragma unroll
    for (int p = 0; p < 4; ++p) acc[a][p] = (f32x4)0.f;
  #pragma unroll
  for (int kc = 0; kc < 8; ++kc) {
    short8 af[4], bfr[4];
    #pragma unroll
    for (int mf = 0; mf < 4; ++mf) {
      int rr = mf * 16 + (lane & 15);
      int c = kc * 4 + (lane >> 4);
      af[mf] = *(const short8*)(Hb + rr * 256 + ((c ^ (rr & 7)) << 3));
    }
    #pragma unroll
    for (int nf = 0; nf < 4; ++nf)
      bfr[nf] = *(const short8*)&Wb[(size_t)(((wn * 4 + nf) * 8 + kc) * 64 + lane) * 8];
    #pragma unroll
    for (int mf = 0; mf < 4; ++mf)
      #pragma unroll
      for (int nf = 0; nf < 4; ++nf)
        acc[mf][nf] = __builtin_amdgcn_mfma_f32_16x16x32_bf16(af[mf], bfr[nf], acc[mf][nf], 0, 0, 0);
  }

  float bbv[4];
  #pragma unroll
  for (int nf = 0; nf < 4; ++nf) bbv[nf] = bb[wn * 64 + nf * 16 + (lane & 15)];
  #pragma unroll
  for (int mf = 0; mf < 4; ++mf)
    #pragma unroll
    for (int nf = 0; nf < 4; ++nf)
      #pragma unroll
      for (int j = 0; j < 4; ++j) {
        int rr = mf * 16 + ((lane >> 4) * 4) + j;
        int col = wn * 64 + nf * 16 + (lane & 15);
        out[(size_t)(row0 + rr) * 384 + 128 + col] = acc[mf][nf][j] + bbv[nf];
      }
}

__global__ __launch_bounds__(256, 4) void fused(
    const float* __restrict__ user,
    const unsigned short* __restrict__ m1b, const unsigned short* __restrict__ m2b,
    const int* __restrict__ am,
    const unsigned short* __restrict__ risb, const unsigned short* __restrict__ meanb,
    const unsigned short* __restrict__ W1f, const unsigned short* __restrict__ W2f,
    const unsigned short* __restrict__ W3f, const unsigned short* __restrict__ W4f,
    const float* __restrict__ b1, const float* __restrict__ b2,
    const float* __restrict__ b3, const float* __restrict__ b4,
    float* __restrict__ out0, float* __restrict__ out1) {
  __shared__ unsigned short Hb[64 * 256];
  if (blockIdx.x < 1024)
    mlp_body<0>(blockIdx.x, Hb, user, m1b, m2b, am, risb, meanb,
                W1f, W2f, b1, b2, out0);
  else
    mlp_body<1>(blockIdx.x - 1024, Hb, user, m1b, m2b, am, risb, meanb,
                W3f, W4f, b3, b4, out1);
}

// ---------------------------------------------------------------------------
extern "C" void kernel_launch(void* const* d_in, const int* in_sizes, int n_in,
                              void* d_out, int out_size, void* d_ws, size_t ws_size,
                              hipStream_t stream) {
  const float* user = (const float*)d_in[0];
  const float* ris  = (const float*)d_in[1];
  const float* W1 = (const float*)d_in[4];
  const float* b1 = (const float*)d_in[5];
  const float* W2 = (const float*)d_in[6];
  const float* b2 = (const float*)d_in[7];
  const float* W3 = (const float*)d_in[8];
  const float* b3 = (const float*)d_in[9];
  const float* W4 = (const float*)d_in[10];
  const float* b4 = (const float*)d_in[11];

  float* out0 = (float*)d_out;                         // (65536, 384)
  float* out1 = out0 + (size_t)65536 * 384;            // (1024, 384)

  char* ws = (char*)d_ws;
  unsigned short* m1b   = (unsigned short*)(ws);            // 131072 bf16
  unsigned short* m2b   = (unsigned short*)(ws + 262144);
  int*            amv   = (int*)(ws + 524288);              // 131072 i32
  unsigned short* meanb = (unsigned short*)(ws + 1048576);
  unsigned short* risb  = (unsigned short*)(ws + 1310720);
  unsigned short* W1f   = (unsigned short*)(ws + 1572864);  // 98304 bf16
  unsigned short* W2f   = (unsigned short*)(ws + 1769472);  // 65536 bf16
  unsigned short* W3f   = (unsigned short*)(ws + 1900544);
  unsigned short* W4f   = (unsigned short*)(ws + 2031616);
  unsigned short* Hu    = (unsigned short*)(ws + 2162688);  // 4*65536*64 bf16 = 32 MiB
  unsigned short* Hr    = (unsigned short*)(ws + 2162688 + 33554432);  // 512 KiB
  const size_t WS_NEED = 2162688 + 33554432 + 524288;

  hipLaunchKernelGGL(prep, dim3(1664), dim3(256), 0, stream,
                     user, ris, W1, W2, W3, W4,
                     m1b, m2b, amv, meanb, risb,
                     W1f, W2f, W3f, W4f, out0, out1);
  if (ws_size >= WS_NEED) {
    hipLaunchKernelGGL(l1k, dim3(1040), dim3(256), 0, stream,
                       user, m1b, m2b, amv, risb, meanb,
                       W1f, W3f, b1, b3, Hu, Hr);
    hipLaunchKernelGGL(l2k, dim3(1040), dim3(256), 0, stream,
                       Hu, Hr, W2f, W4f, b2, b4, out0, out1);
  } else {
    hipLaunchKernelGGL(fused, dim3(1040), dim3(256), 0, stream,
                       user, m1b, m2b, amv, risb, meanb,
                       W1f, W2f, W3f, W4f, b1, b2, b3, b4, out0, out1);
  }
}